// Round 1
// baseline (194.586 us; speedup 1.0000x reference)
//
#include <hip/hip_runtime.h>

#define NA_   4096
#define NB_   4000
#define NANG_ 8000
#define NAC_  4000
#define ND_   12000
#define NDC_  6000
#define NI_   2000
#define EPS_  1e-12f
#define COUL_ 332.33f

struct F3 { float x, y, z; };

__device__ inline F3 ldp(const float* __restrict__ p, int i) {
    F3 r; r.x = p[3*i]; r.y = p[3*i+1]; r.z = p[3*i+2]; return r;
}
__device__ inline F3 sub3(F3 a, F3 b) { return {a.x-b.x, a.y-b.y, a.z-b.z}; }
__device__ inline float dot3(F3 a, F3 b) { return a.x*b.x + a.y*b.y + a.z*b.z; }
__device__ inline F3 cross3(F3 a, F3 b) {
    return {a.y*b.z - a.z*b.y, a.z*b.x - a.x*b.z, a.x*b.y - a.y*b.x};
}

__device__ inline float angle_(F3 p0, F3 p1, F3 p2) {
    F3 u = sub3(p0, p1), v = sub3(p2, p1);
    float c = dot3(u, v) * rsqrtf(dot3(u, u) * dot3(v, v) + EPS_);
    c = fminf(fmaxf(c, -1.0f + 1e-7f), 1.0f - 1e-7f);
    return acosf(c);
}

__device__ inline float dihedral_(F3 p0, F3 p1, F3 p2, F3 p3) {
    F3 b1 = sub3(p1, p0), b2 = sub3(p2, p1), b3 = sub3(p3, p2);
    F3 n1 = cross3(b1, b2), n2 = cross3(b2, b3);
    float ib = rsqrtf(dot3(b2, b2) + EPS_);
    F3 b2n = {b2.x * ib, b2.y * ib, b2.z * ib};
    float y = dot3(cross3(n1, b2n), n2);
    float x = dot3(n1, n2);
    return atan2f(y, x);
}

__device__ inline void block_reduce_add(double local, double* acc) {
    __shared__ double sd[256];
    int tid = threadIdx.x;
    sd[tid] = local;
    __syncthreads();
    for (int s = 128; s > 0; s >>= 1) {
        if (tid < s) sd[tid] += sd[tid + s];
        __syncthreads();
    }
    if (tid == 0) atomicAdd(acc, sd[0]);
}

__global__ void init_k(double* __restrict__ acc) {
    acc[0] = 0.0;
}

// One block handles rows b and NA-1-b: exactly 4095 j-iterations per block.
__global__ __launch_bounds__(256) void pair_k(
    const float* __restrict__ pos, const float* __restrict__ q,
    const float* __restrict__ eps, const float* __restrict__ sig,
    const float* __restrict__ mask, double* __restrict__ acc)
{
    int b = blockIdx.x;
    int tid = threadIdx.x;
    double local = 0.0;
    #pragma unroll
    for (int rr = 0; rr < 2; ++rr) {
        int i = (rr == 0) ? b : (NA_ - 1 - b);
        float xi = pos[3*i], yi = pos[3*i+1], zi = pos[3*i+2];
        float qi = q[i] * COUL_;
        float ei = eps[i];
        float si = sig[i];
        const float* __restrict__ mrow = mask + (size_t)i * NA_;
        for (int j = i + 1 + tid; j < NA_; j += 256) {
            float dx = xi - pos[3*j];
            float dy = yi - pos[3*j+1];
            float dz = zi - pos[3*j+2];
            float r2 = dx*dx + dy*dy + dz*dz + EPS_;
            float inv_r = rsqrtf(r2);
            float eij = sqrtf(ei * eps[j]);
            float sij = 0.5f * (si + sig[j]);
            float s_r = sij * inv_r;
            float s2 = s_r * s_r;
            float sr6 = s2 * s2 * s2;
            float e = 4.0f * eij * (sr6 * sr6 - sr6) + qi * q[j] * inv_r;
            local += (double)(mrow[j] * e);
        }
    }
    block_reduce_add(local, acc);
}

__global__ __launch_bounds__(256) void bonded_k(
    const float* __restrict__ pos,
    const float* __restrict__ bond_c,  const float* __restrict__ ang_c,
    const float* __restrict__ angc_c,  const float* __restrict__ dih_c,
    const float* __restrict__ dihc_c,  const float* __restrict__ imp_c,
    const int* __restrict__ bond_i,  const int* __restrict__ ang_i,
    const int* __restrict__ angc_i,  const int* __restrict__ dih_i,
    const int* __restrict__ dihc_i,  const int* __restrict__ imp_i,
    double* __restrict__ acc)
{
    int t = blockIdx.x * 256 + threadIdx.x;
    float e = 0.0f;
    if (t < NB_) {
        int k = t;
        int i0 = bond_i[3*k], i1 = bond_i[3*k+1], ty = bond_i[3*k+2];
        F3 d = sub3(ldp(pos, i0), ldp(pos, i1));
        float r = sqrtf(dot3(d, d) + EPS_);
        float dr = r - bond_c[2*ty+1];
        e = bond_c[2*ty] * dr * dr;
    } else if (t < NB_ + NANG_) {
        int k = t - NB_;
        int i0 = ang_i[4*k], i1 = ang_i[4*k+1], i2 = ang_i[4*k+2], ty = ang_i[4*k+3];
        float th = angle_(ldp(pos, i0), ldp(pos, i1), ldp(pos, i2));
        float dt = th - ang_c[2*ty+1];
        e = ang_c[2*ty] * dt * dt;
    } else if (t < NB_ + NANG_ + NAC_) {
        int k = t - NB_ - NANG_;
        int i0 = angc_i[4*k], i1 = angc_i[4*k+1], i2 = angc_i[4*k+2], ty = angc_i[4*k+3];
        F3 p0 = ldp(pos, i0), p1 = ldp(pos, i1), p2 = ldp(pos, i2);
        float th = angle_(p0, p1, p2);
        F3 d13 = sub3(p0, p2);
        float r13 = sqrtf(dot3(d13, d13) + EPS_);
        float dt = th - angc_c[4*ty+1];
        float du = r13 - angc_c[4*ty+3];
        e = angc_c[4*ty] * dt * dt + angc_c[4*ty+2] * du * du;
    } else if (t < NB_ + NANG_ + NAC_ + ND_) {
        int k = t - NB_ - NANG_ - NAC_;
        int i0 = dih_i[5*k], i1 = dih_i[5*k+1], i2 = dih_i[5*k+2],
            i3 = dih_i[5*k+3], ty = dih_i[5*k+4];
        float phi = dihedral_(ldp(pos, i0), ldp(pos, i1), ldp(pos, i2), ldp(pos, i3));
        float c = cosf(phi);
        const float* A = dih_c + 5*ty;
        e = A[0] + c * (A[1] + c * (A[2] + c * (A[3] + c * A[4])));
    } else if (t < NB_ + NANG_ + NAC_ + ND_ + NDC_) {
        int k = t - NB_ - NANG_ - NAC_ - ND_;
        int i0 = dihc_i[5*k], i1 = dihc_i[5*k+1], i2 = dihc_i[5*k+2],
            i3 = dihc_i[5*k+3], ty = dihc_i[5*k+4];
        float phi = dihedral_(ldp(pos, i0), ldp(pos, i1), ldp(pos, i2), ldp(pos, i3));
        e = dihc_c[4*ty] * (1.0f + cosf(dihc_c[4*ty+1] * phi - dihc_c[4*ty+2]));
    } else if (t < NB_ + NANG_ + NAC_ + ND_ + NDC_ + NI_) {
        int k = t - NB_ - NANG_ - NAC_ - ND_ - NDC_;
        int i0 = imp_i[5*k], i1 = imp_i[5*k+1], i2 = imp_i[5*k+2],
            i3 = imp_i[5*k+3], ty = imp_i[5*k+4];
        float chi = dihedral_(ldp(pos, i0), ldp(pos, i1), ldp(pos, i2), ldp(pos, i3));
        float dc = chi - imp_c[2*ty+1];
        e = imp_c[2*ty] * dc * dc;
    }
    block_reduce_add((double)e, acc);
}

__global__ void fin_k(const double* __restrict__ acc, float* __restrict__ out) {
    out[0] = (float)acc[0];
}

extern "C" void kernel_launch(void* const* d_in, const int* in_sizes, int n_in,
                              void* d_out, int out_size, void* d_ws, size_t ws_size,
                              hipStream_t stream) {
    const float* pos  = (const float*)d_in[0];
    const float* q    = (const float*)d_in[1];
    const float* eps  = (const float*)d_in[2];
    const float* sig  = (const float*)d_in[3];
    const float* mask = (const float*)d_in[4];
    const float* bond_c = (const float*)d_in[5];
    const float* ang_c  = (const float*)d_in[6];
    const float* angc_c = (const float*)d_in[7];
    const float* dih_c  = (const float*)d_in[8];
    const float* dihc_c = (const float*)d_in[9];
    const float* imp_c  = (const float*)d_in[10];
    const int* bond_i = (const int*)d_in[11];
    const int* ang_i  = (const int*)d_in[12];
    const int* angc_i = (const int*)d_in[13];
    const int* dih_i  = (const int*)d_in[14];
    const int* dihc_i = (const int*)d_in[15];
    const int* imp_i  = (const int*)d_in[16];
    // d_in[17] = pair_idx: deterministic triu_indices -- intentionally unread.

    double* acc = (double*)d_ws;   // ws is poisoned each launch; init_k zeroes it.
    float* out = (float*)d_out;

    hipLaunchKernelGGL(init_k, dim3(1), dim3(1), 0, stream, acc);
    hipLaunchKernelGGL(pair_k, dim3(NA_ / 2), dim3(256), 0, stream,
                       pos, q, eps, sig, mask, acc);
    int nbonded = NB_ + NANG_ + NAC_ + ND_ + NDC_ + NI_;
    hipLaunchKernelGGL(bonded_k, dim3((nbonded + 255) / 256), dim3(256), 0, stream,
                       pos, bond_c, ang_c, angc_c, dih_c, dihc_c, imp_c,
                       bond_i, ang_i, angc_i, dih_i, dihc_i, imp_i, acc);
    hipLaunchKernelGGL(fin_k, dim3(1), dim3(1), 0, stream, acc, out);
}

// Round 2
// 180.852 us; speedup vs baseline: 1.0759x; 1.0759x over previous
//
#include <hip/hip_runtime.h>

#define NA_   4096
#define NB_   4000
#define NANG_ 8000
#define NAC_  4000
#define ND_   12000
#define NDC_  6000
#define NI_   2000
#define EPS_  1e-12f
#define COUL_ 332.33f

#define NBONDED (NB_ + NANG_ + NAC_ + ND_ + NDC_ + NI_)   // 36000
#define NPB   (NA_ / 2)                                    // 2048 pair blocks
#define NBB   ((NBONDED + 255) / 256)                      // 141 bonded blocks
#define NBLK  (NPB + NBB)
#define TILE  1024
#define NTILE (NA_ / TILE)

struct F3 { float x, y, z; };

__device__ inline F3 ldp(const float* __restrict__ p, int i) {
    F3 r; r.x = p[3*i]; r.y = p[3*i+1]; r.z = p[3*i+2]; return r;
}
__device__ inline F3 sub3(F3 a, F3 b) { return {a.x-b.x, a.y-b.y, a.z-b.z}; }
__device__ inline float dot3(F3 a, F3 b) { return a.x*b.x + a.y*b.y + a.z*b.z; }
__device__ inline F3 cross3(F3 a, F3 b) {
    return {a.y*b.z - a.z*b.y, a.z*b.x - a.x*b.z, a.x*b.y - a.y*b.x};
}

__device__ inline float angle_(F3 p0, F3 p1, F3 p2) {
    F3 u = sub3(p0, p1), v = sub3(p2, p1);
    float c = dot3(u, v) * rsqrtf(dot3(u, u) * dot3(v, v) + EPS_);
    c = fminf(fmaxf(c, -1.0f + 1e-7f), 1.0f - 1e-7f);
    return acosf(c);
}

__device__ inline float dihedral_(F3 p0, F3 p1, F3 p2, F3 p3) {
    F3 b1 = sub3(p1, p0), b2 = sub3(p2, p1), b3 = sub3(p3, p2);
    F3 n1 = cross3(b1, b2), n2 = cross3(b2, b3);
    float ib = rsqrtf(dot3(b2, b2) + EPS_);
    F3 b2n = {b2.x * ib, b2.y * ib, b2.z * ib};
    return atan2f(dot3(cross3(n1, b2n), n2), dot3(n1, n2));
}

// Fused kernel: blocks [0,NPB) do the nonbonded pair sum (rows b and NA-1-b,
// exactly 4095 j-iterations per block -> perfect balance); blocks [NPB,NBLK)
// do the bonded terms. Each block writes one double partial to ws (all slots
// written every launch -> no init kernel needed).
__global__ __launch_bounds__(256) void main_k(
    const float* __restrict__ pos, const float* __restrict__ q,
    const float* __restrict__ eps, const float* __restrict__ sig,
    const float* __restrict__ mask,
    const float* __restrict__ bond_c,  const float* __restrict__ ang_c,
    const float* __restrict__ angc_c,  const float* __restrict__ dih_c,
    const float* __restrict__ dihc_c,  const float* __restrict__ imp_c,
    const int* __restrict__ bond_i,  const int* __restrict__ ang_i,
    const int* __restrict__ angc_i,  const int* __restrict__ dih_i,
    const int* __restrict__ dihc_i,  const int* __restrict__ imp_i,
    double* __restrict__ partials)
{
    // 24 KB SoA stage + 2 KB reduce -> 26 KB LDS -> 6 blocks/CU (24 waves/CU)
    __shared__ float sx[TILE], sy[TILE], sz[TILE], sq[TILE], se[TILE], ss[TILE];
    __shared__ double sred[256];
    const int tid = threadIdx.x;
    const int bid = blockIdx.x;
    double local = 0.0;

    if (bid < NPB) {
        const float SQC = 18.2299835f;  // sqrtf(332.33)
        const int iA = bid, iB = NA_ - 1 - bid;
        // Row-atom scalars from global (row atom may precede staged tiles).
        const float xA = pos[3*iA], yA = pos[3*iA+1], zA = pos[3*iA+2];
        const float qA = q[iA] * SQC, eA = sqrtf(eps[iA]), sA = sig[iA];
        const float xB = pos[3*iB], yB = pos[3*iB+1], zB = pos[3*iB+2];
        const float qB = q[iB] * SQC, eB = sqrtf(eps[iB]), sB = sig[iB];

        const int t0 = (iA + 1) >> 10;          // first tile any row needs
        for (int t = t0; t < NTILE; ++t) {
            const int tbase = t << 10;
            __syncthreads();                     // protect previous-tile reads
            for (int a = tid; a < TILE; a += 256) {
                const int g = tbase + a;
                sx[a] = pos[3*g]; sy[a] = pos[3*g+1]; sz[a] = pos[3*g+2];
                sq[a] = q[g] * SQC; se[a] = sqrtf(eps[g]); ss[a] = sig[g];
            }
            __syncthreads();

            #pragma unroll
            for (int rr = 0; rr < 2; ++rr) {
                const int   i  = rr ? iB : iA;
                const float xi = rr ? xB : xA, yi = rr ? yB : yA, zi = rr ? zB : zA;
                const float qi = rr ? qB : qA, ei = rr ? eB : eA, si = rr ? sB : sA;
                const int jlo = i + 1;
                if (jlo >= tbase + TILE) continue;   // row done before this tile
                const int a0 = (jlo > tbase) ? (jlo & ~3) : tbase;
                const int j4 = a0 + 4 * tid;         // one float4 group/thread
                if (j4 < tbase + TILE) {
                    const int l = j4 - tbase;
                    const float4 m4 = *(const float4*)(mask + (size_t)i * NA_ + j4);
                    const float4 x4 = *(const float4*)&sx[l];
                    const float4 y4 = *(const float4*)&sy[l];
                    const float4 z4 = *(const float4*)&sz[l];
                    const float4 q4 = *(const float4*)&sq[l];
                    const float4 e4 = *(const float4*)&se[l];
                    const float4 s4 = *(const float4*)&ss[l];
                    float mv[4], xv[4], yv[4], zv[4], qv[4], ev[4], sv[4];
                    *(float4*)mv = m4; *(float4*)xv = x4; *(float4*)yv = y4;
                    *(float4*)zv = z4; *(float4*)qv = q4; *(float4*)ev = e4;
                    *(float4*)sv = s4;
                    #pragma unroll
                    for (int k = 0; k < 4; ++k) {
                        const int j = j4 + k;
                        const float dx = xi - xv[k];
                        const float dy = yi - yv[k];
                        const float dz = zi - zv[k];
                        const float r2 = dx*dx + dy*dy + dz*dz + EPS_;
                        const float inv_r = rsqrtf(r2);
                        const float eij = ei * ev[k];            // sqrt(ei*ej)
                        const float sij = 0.5f * (si + sv[k]);
                        const float sr  = sij * inv_r;
                        const float s2  = sr * sr;
                        const float sr6 = s2 * s2 * s2;
                        const float en  = 4.0f * eij * (sr6*sr6 - sr6)
                                        + qi * qv[k] * inv_r;    // COUL*qi*qj/r
                        if (j > i) local += (double)(mv[k] * en);
                    }
                }
            }
        }
    } else {
        const int t = (bid - NPB) * 256 + tid;
        float e = 0.0f;
        if (t < NB_) {
            const int k = t;
            const int i0 = bond_i[3*k], i1 = bond_i[3*k+1], ty = bond_i[3*k+2];
            F3 d = sub3(ldp(pos, i0), ldp(pos, i1));
            const float r = sqrtf(dot3(d, d) + EPS_);
            const float dr = r - bond_c[2*ty+1];
            e = bond_c[2*ty] * dr * dr;
        } else if (t < NB_ + NANG_) {
            const int k = t - NB_;
            const int i0 = ang_i[4*k], i1 = ang_i[4*k+1], i2 = ang_i[4*k+2], ty = ang_i[4*k+3];
            const float th = angle_(ldp(pos, i0), ldp(pos, i1), ldp(pos, i2));
            const float dt = th - ang_c[2*ty+1];
            e = ang_c[2*ty] * dt * dt;
        } else if (t < NB_ + NANG_ + NAC_) {
            const int k = t - NB_ - NANG_;
            const int i0 = angc_i[4*k], i1 = angc_i[4*k+1], i2 = angc_i[4*k+2], ty = angc_i[4*k+3];
            const F3 p0 = ldp(pos, i0), p1 = ldp(pos, i1), p2 = ldp(pos, i2);
            const float th = angle_(p0, p1, p2);
            const F3 d13 = sub3(p0, p2);
            const float r13 = sqrtf(dot3(d13, d13) + EPS_);
            const float dt = th - angc_c[4*ty+1];
            const float du = r13 - angc_c[4*ty+3];
            e = angc_c[4*ty] * dt * dt + angc_c[4*ty+2] * du * du;
        } else if (t < NB_ + NANG_ + NAC_ + ND_) {
            const int k = t - NB_ - NANG_ - NAC_;
            const int i0 = dih_i[5*k], i1 = dih_i[5*k+1], i2 = dih_i[5*k+2],
                      i3 = dih_i[5*k+3], ty = dih_i[5*k+4];
            const float phi = dihedral_(ldp(pos,i0), ldp(pos,i1), ldp(pos,i2), ldp(pos,i3));
            const float c = cosf(phi);
            const float* A = dih_c + 5*ty;
            e = A[0] + c*(A[1] + c*(A[2] + c*(A[3] + c*A[4])));
        } else if (t < NB_ + NANG_ + NAC_ + ND_ + NDC_) {
            const int k = t - NB_ - NANG_ - NAC_ - ND_;
            const int i0 = dihc_i[5*k], i1 = dihc_i[5*k+1], i2 = dihc_i[5*k+2],
                      i3 = dihc_i[5*k+3], ty = dihc_i[5*k+4];
            const float phi = dihedral_(ldp(pos,i0), ldp(pos,i1), ldp(pos,i2), ldp(pos,i3));
            e = dihc_c[4*ty] * (1.0f + cosf(dihc_c[4*ty+1] * phi - dihc_c[4*ty+2]));
        } else if (t < NBONDED) {
            const int k = t - NB_ - NANG_ - NAC_ - ND_ - NDC_;
            const int i0 = imp_i[5*k], i1 = imp_i[5*k+1], i2 = imp_i[5*k+2],
                      i3 = imp_i[5*k+3], ty = imp_i[5*k+4];
            const float chi = dihedral_(ldp(pos,i0), ldp(pos,i1), ldp(pos,i2), ldp(pos,i3));
            const float dc = chi - imp_c[2*ty+1];
            e = imp_c[2*ty] * dc * dc;
        }
        local = (double)e;
    }

    sred[tid] = local;
    __syncthreads();
    for (int s = 128; s > 0; s >>= 1) {
        if (tid < s) sred[tid] += sred[tid + s];
        __syncthreads();
    }
    if (tid == 0) partials[bid] = sred[0];
}

__global__ __launch_bounds__(256) void fin_k(const double* __restrict__ partials,
                                             float* __restrict__ out) {
    __shared__ double sred[256];
    const int tid = threadIdx.x;
    double s = 0.0;
    for (int i = tid; i < NBLK; i += 256) s += partials[i];
    sred[tid] = s;
    __syncthreads();
    for (int st = 128; st > 0; st >>= 1) {
        if (tid < st) sred[tid] += sred[tid + st];
        __syncthreads();
    }
    if (tid == 0) out[0] = (float)sred[0];
}

extern "C" void kernel_launch(void* const* d_in, const int* in_sizes, int n_in,
                              void* d_out, int out_size, void* d_ws, size_t ws_size,
                              hipStream_t stream) {
    const float* pos  = (const float*)d_in[0];
    const float* q    = (const float*)d_in[1];
    const float* eps  = (const float*)d_in[2];
    const float* sig  = (const float*)d_in[3];
    const float* mask = (const float*)d_in[4];
    const float* bond_c = (const float*)d_in[5];
    const float* ang_c  = (const float*)d_in[6];
    const float* angc_c = (const float*)d_in[7];
    const float* dih_c  = (const float*)d_in[8];
    const float* dihc_c = (const float*)d_in[9];
    const float* imp_c  = (const float*)d_in[10];
    const int* bond_i = (const int*)d_in[11];
    const int* ang_i  = (const int*)d_in[12];
    const int* angc_i = (const int*)d_in[13];
    const int* dih_i  = (const int*)d_in[14];
    const int* dihc_i = (const int*)d_in[15];
    const int* imp_i  = (const int*)d_in[16];
    // d_in[17] = pair_idx: deterministic triu_indices -- intentionally unread.

    double* partials = (double*)d_ws;   // NBLK doubles; every slot written.
    float* out = (float*)d_out;

    hipLaunchKernelGGL(main_k, dim3(NBLK), dim3(256), 0, stream,
                       pos, q, eps, sig, mask,
                       bond_c, ang_c, angc_c, dih_c, dihc_c, imp_c,
                       bond_i, ang_i, angc_i, dih_i, dihc_i, imp_i, partials);
    hipLaunchKernelGGL(fin_k, dim3(1), dim3(256), 0, stream, partials, out);
}

// Round 3
// 169.058 us; speedup vs baseline: 1.1510x; 1.0698x over previous
//
#include <hip/hip_runtime.h>

#define NA_   4096
#define NB_   4000
#define NANG_ 8000
#define NAC_  4000
#define ND_   12000
#define NDC_  6000
#define NI_   2000
#define EPS_  1e-12f

#define NBONDED (NB_ + NANG_ + NAC_ + ND_ + NDC_ + NI_)   // 36000
#define NPB   1024                                         // pair blocks (4 rows each)
#define NBB   ((NBONDED + 255) / 256)                      // 141 bonded blocks
#define NBLK  (NPB + NBB)
#define TILE  1024
#define NTILE (NA_ / TILE)

struct F3 { float x, y, z; };

__device__ inline F3 ldp(const float* __restrict__ p, int i) {
    F3 r; r.x = p[3*i]; r.y = p[3*i+1]; r.z = p[3*i+2]; return r;
}
__device__ inline F3 sub3(F3 a, F3 b) { return {a.x-b.x, a.y-b.y, a.z-b.z}; }
__device__ inline float dot3(F3 a, F3 b) { return a.x*b.x + a.y*b.y + a.z*b.z; }
__device__ inline F3 cross3(F3 a, F3 b) {
    return {a.y*b.z - a.z*b.y, a.z*b.x - a.x*b.z, a.x*b.y - a.y*b.x};
}

__device__ inline float angle_(F3 p0, F3 p1, F3 p2) {
    F3 u = sub3(p0, p1), v = sub3(p2, p1);
    float c = dot3(u, v) * rsqrtf(dot3(u, u) * dot3(v, v) + EPS_);
    c = fminf(fmaxf(c, -1.0f + 1e-7f), 1.0f - 1e-7f);
    return acosf(c);
}

__device__ inline float dihedral_(F3 p0, F3 p1, F3 p2, F3 p3) {
    F3 b1 = sub3(p1, p0), b2 = sub3(p2, p1), b3 = sub3(p3, p2);
    F3 n1 = cross3(b1, b2), n2 = cross3(b2, b3);
    float ib = rsqrtf(dot3(b2, b2) + EPS_);
    F3 b2n = {b2.x * ib, b2.y * ib, b2.z * ib};
    return atan2f(dot3(cross3(n1, b2n), n2), dot3(n1, n2));
}

// Blocks [0,NPB): nonbonded. Block b owns rows {2b, 2b+1, 4094-2b, 4095-2b}
// -> exactly 8190 pairs/block (perfect balance). j-atom data staged in LDS
// per 1024-tile; each thread reads its float4 j-group from LDS ONCE and
// reuses it across all 4 rows (register caching). Blocks [NPB,NBLK): bonded.
__global__ __launch_bounds__(256) void main_k(
    const float* __restrict__ pos, const float* __restrict__ q,
    const float* __restrict__ eps, const float* __restrict__ sig,
    const float* __restrict__ mask,
    const float* __restrict__ bond_c,  const float* __restrict__ ang_c,
    const float* __restrict__ angc_c,  const float* __restrict__ dih_c,
    const float* __restrict__ dihc_c,  const float* __restrict__ imp_c,
    const int* __restrict__ bond_i,  const int* __restrict__ ang_i,
    const int* __restrict__ angc_i,  const int* __restrict__ dih_i,
    const int* __restrict__ dihc_i,  const int* __restrict__ imp_i,
    double* __restrict__ partials)
{
    __shared__ float sx[TILE], sy[TILE], sz[TILE], sq[TILE], se[TILE], ss[TILE];
    __shared__ double sred[256];
    const int tid = threadIdx.x;
    const int bid = blockIdx.x;
    double local = 0.0;

    if (bid < NPB) {
        const float SQC = 18.2299835f;  // sqrtf(332.33)
        int   irow[4];
        float rx[4], ry[4], rz[4], rq[4], re_[4], rs[4];
        irow[0] = 2 * bid;       irow[1] = 2 * bid + 1;
        irow[2] = 4094 - 2 * bid; irow[3] = 4095 - 2 * bid;
        #pragma unroll
        for (int r = 0; r < 4; ++r) {
            const int i = irow[r];
            rx[r] = pos[3*i]; ry[r] = pos[3*i+1]; rz[r] = pos[3*i+2];
            rq[r] = q[i] * SQC; re_[r] = sqrtf(eps[i]); rs[r] = sig[i];
        }

        const int t0 = (2 * bid + 1) >> 10;   // first tile the lowest row needs
        for (int t = t0; t < NTILE; ++t) {
            const int tbase = t << 10;
            __syncthreads();                   // protect previous-tile reads
            {
                // Fully vectorized stage: 4 atoms/thread, 6 float4 loads.
                const int a0 = 4 * tid;
                const int g0 = tbase + a0;
                const float4 pa = *(const float4*)(pos + 3*g0);
                const float4 pb = *(const float4*)(pos + 3*g0 + 4);
                const float4 pc = *(const float4*)(pos + 3*g0 + 8);
                const float4 q4 = *(const float4*)(q   + g0);
                const float4 e4 = *(const float4*)(eps + g0);
                const float4 s4 = *(const float4*)(sig + g0);
                *(float4*)&sx[a0] = make_float4(pa.x, pa.w, pb.z, pc.y);
                *(float4*)&sy[a0] = make_float4(pa.y, pb.x, pb.w, pc.z);
                *(float4*)&sz[a0] = make_float4(pa.z, pb.y, pc.x, pc.w);
                *(float4*)&sq[a0] = make_float4(q4.x*SQC, q4.y*SQC, q4.z*SQC, q4.w*SQC);
                *(float4*)&se[a0] = make_float4(sqrtf(e4.x), sqrtf(e4.y),
                                                sqrtf(e4.z), sqrtf(e4.w));
                *(float4*)&ss[a0] = s4;
            }
            __syncthreads();

            // Load this thread's j-group once; reuse across 4 rows.
            const int l  = 4 * tid;
            const int j4 = tbase + l;
            float xv[4], yv[4], zv[4], qv[4], ev[4], sv[4];
            *(float4*)xv = *(const float4*)&sx[l];
            *(float4*)yv = *(const float4*)&sy[l];
            *(float4*)zv = *(const float4*)&sz[l];
            *(float4*)qv = *(const float4*)&sq[l];
            *(float4*)ev = *(const float4*)&se[l];
            *(float4*)sv = *(const float4*)&ss[l];

            #pragma unroll
            for (int r = 0; r < 4; ++r) {
                const int i = irow[r];
                if (i + 1 >= tbase + TILE) continue;  // block-uniform skip
                if (j4 + 3 > i) {                     // wave-coherent skip
                    const float4 m4 = *(const float4*)(mask + (size_t)i * NA_ + j4);
                    float mv[4]; *(float4*)mv = m4;
                    const float xi = rx[r], yi = ry[r], zi = rz[r];
                    const float qi = rq[r], ei = re_[r], si = rs[r];
                    float fsum = 0.0f;
                    #pragma unroll
                    for (int k = 0; k < 4; ++k) {
                        const int j = j4 + k;
                        const float dx = xi - xv[k];
                        const float dy = yi - yv[k];
                        const float dz = zi - zv[k];
                        const float r2 = dx*dx + dy*dy + dz*dz + EPS_;
                        const float inv_r = rsqrtf(r2);
                        const float eij = ei * ev[k];
                        const float sij = 0.5f * (si + sv[k]);
                        const float sr  = sij * inv_r;
                        const float s2  = sr * sr;
                        const float sr6 = s2 * s2 * s2;
                        const float en  = 4.0f * eij * (sr6*sr6 - sr6)
                                        + qi * qv[k] * inv_r;
                        fsum += (j > i) ? mv[k] * en : 0.0f;
                    }
                    local += (double)fsum;
                }
            }
        }
    } else {
        const int t = (bid - NPB) * 256 + tid;
        float e = 0.0f;
        if (t < NB_) {
            const int k = t;
            const int i0 = bond_i[3*k], i1 = bond_i[3*k+1], ty = bond_i[3*k+2];
            F3 d = sub3(ldp(pos, i0), ldp(pos, i1));
            const float r = sqrtf(dot3(d, d) + EPS_);
            const float dr = r - bond_c[2*ty+1];
            e = bond_c[2*ty] * dr * dr;
        } else if (t < NB_ + NANG_) {
            const int k = t - NB_;
            const int i0 = ang_i[4*k], i1 = ang_i[4*k+1], i2 = ang_i[4*k+2], ty = ang_i[4*k+3];
            const float th = angle_(ldp(pos, i0), ldp(pos, i1), ldp(pos, i2));
            const float dt = th - ang_c[2*ty+1];
            e = ang_c[2*ty] * dt * dt;
        } else if (t < NB_ + NANG_ + NAC_) {
            const int k = t - NB_ - NANG_;
            const int i0 = angc_i[4*k], i1 = angc_i[4*k+1], i2 = angc_i[4*k+2], ty = angc_i[4*k+3];
            const F3 p0 = ldp(pos, i0), p1 = ldp(pos, i1), p2 = ldp(pos, i2);
            const float th = angle_(p0, p1, p2);
            const F3 d13 = sub3(p0, p2);
            const float r13 = sqrtf(dot3(d13, d13) + EPS_);
            const float dt = th - angc_c[4*ty+1];
            const float du = r13 - angc_c[4*ty+3];
            e = angc_c[4*ty] * dt * dt + angc_c[4*ty+2] * du * du;
        } else if (t < NB_ + NANG_ + NAC_ + ND_) {
            const int k = t - NB_ - NANG_ - NAC_;
            const int i0 = dih_i[5*k], i1 = dih_i[5*k+1], i2 = dih_i[5*k+2],
                      i3 = dih_i[5*k+3], ty = dih_i[5*k+4];
            const float phi = dihedral_(ldp(pos,i0), ldp(pos,i1), ldp(pos,i2), ldp(pos,i3));
            const float c = cosf(phi);
            const float* A = dih_c + 5*ty;
            e = A[0] + c*(A[1] + c*(A[2] + c*(A[3] + c*A[4])));
        } else if (t < NB_ + NANG_ + NAC_ + ND_ + NDC_) {
            const int k = t - NB_ - NANG_ - NAC_ - ND_;
            const int i0 = dihc_i[5*k], i1 = dihc_i[5*k+1], i2 = dihc_i[5*k+2],
                      i3 = dihc_i[5*k+3], ty = dihc_i[5*k+4];
            const float phi = dihedral_(ldp(pos,i0), ldp(pos,i1), ldp(pos,i2), ldp(pos,i3));
            e = dihc_c[4*ty] * (1.0f + cosf(dihc_c[4*ty+1] * phi - dihc_c[4*ty+2]));
        } else if (t < NBONDED) {
            const int k = t - NB_ - NANG_ - NAC_ - ND_ - NDC_;
            const int i0 = imp_i[5*k], i1 = imp_i[5*k+1], i2 = imp_i[5*k+2],
                      i3 = imp_i[5*k+3], ty = imp_i[5*k+4];
            const float chi = dihedral_(ldp(pos,i0), ldp(pos,i1), ldp(pos,i2), ldp(pos,i3));
            const float dc = chi - imp_c[2*ty+1];
            e = imp_c[2*ty] * dc * dc;
        }
        local = (double)e;
    }

    sred[tid] = local;
    __syncthreads();
    for (int s = 128; s > 0; s >>= 1) {
        if (tid < s) sred[tid] += sred[tid + s];
        __syncthreads();
    }
    if (tid == 0) partials[bid] = sred[0];
}

__global__ __launch_bounds__(256) void fin_k(const double* __restrict__ partials,
                                             float* __restrict__ out) {
    __shared__ double sred[256];
    const int tid = threadIdx.x;
    double s = 0.0;
    for (int i = tid; i < NBLK; i += 256) s += partials[i];
    sred[tid] = s;
    __syncthreads();
    for (int st = 128; st > 0; st >>= 1) {
        if (tid < st) sred[tid] += sred[tid + st];
        __syncthreads();
    }
    if (tid == 0) out[0] = (float)sred[0];
}

extern "C" void kernel_launch(void* const* d_in, const int* in_sizes, int n_in,
                              void* d_out, int out_size, void* d_ws, size_t ws_size,
                              hipStream_t stream) {
    const float* pos  = (const float*)d_in[0];
    const float* q    = (const float*)d_in[1];
    const float* eps  = (const float*)d_in[2];
    const float* sig  = (const float*)d_in[3];
    const float* mask = (const float*)d_in[4];
    const float* bond_c = (const float*)d_in[5];
    const float* ang_c  = (const float*)d_in[6];
    const float* angc_c = (const float*)d_in[7];
    const float* dih_c  = (const float*)d_in[8];
    const float* dihc_c = (const float*)d_in[9];
    const float* imp_c  = (const float*)d_in[10];
    const int* bond_i = (const int*)d_in[11];
    const int* ang_i  = (const int*)d_in[12];
    const int* angc_i = (const int*)d_in[13];
    const int* dih_i  = (const int*)d_in[14];
    const int* dihc_i = (const int*)d_in[15];
    const int* imp_i  = (const int*)d_in[16];
    // d_in[17] = pair_idx: deterministic triu_indices -- intentionally unread.

    double* partials = (double*)d_ws;   // NBLK doubles; every slot written.
    float* out = (float*)d_out;

    hipLaunchKernelGGL(main_k, dim3(NBLK), dim3(256), 0, stream,
                       pos, q, eps, sig, mask,
                       bond_c, ang_c, angc_c, dih_c, dihc_c, imp_c,
                       bond_i, ang_i, angc_i, dih_i, dihc_i, imp_i, partials);
    hipLaunchKernelGGL(fin_k, dim3(1), dim3(256), 0, stream, partials, out);
}